// Round 1
// 391.769 us; speedup vs baseline: 1.0697x; 1.0697x over previous
//
#include <hip/hip_runtime.h>
#include <hip/hip_bf16.h>

typedef unsigned short ushort_t;
typedef unsigned int u32;
typedef __attribute__((ext_vector_type(8))) short short8;
typedef short8 __attribute__((may_alias)) short8_ma;
typedef __attribute__((ext_vector_type(4))) float f32x4;
typedef f32x4 __attribute__((may_alias)) f32x4_ma;
typedef __attribute__((ext_vector_type(2))) unsigned int u32x2;
typedef u32x2 __attribute__((may_alias)) u32x2_ma;
typedef __attribute__((ext_vector_type(4))) unsigned int u32x4;
typedef u32x4 __attribute__((may_alias)) u32x4_ma;

#if __has_builtin(__builtin_amdgcn_exp2f)
#define EXP2(x) __builtin_amdgcn_exp2f(x)
#else
#define EXP2(x) exp2f(x)
#endif

__device__ __forceinline__ unsigned short f2bf(float f) {
    union { float f; unsigned int i; } x; x.f = f;
    unsigned int r = x.i + 0x7FFFu + ((x.i >> 16) & 1u);
    return (unsigned short)(r >> 16);
}
__device__ __forceinline__ unsigned int bfround(float f) {
    union { float f; unsigned int i; } x; x.f = f;
    return x.i + 0x7FFFu + ((x.i >> 16) & 1u);
}
// RNE bf16 pair packed in u32: [lo, hi] in memory order.
__device__ __forceinline__ unsigned int pack2bf(float lo, float hi) {
    return __builtin_amdgcn_perm(bfround(hi), bfround(lo), 0x07060302u);
}
// Single-instruction packed f32->bf16 (RNE): dst.lo = bf16(lo), dst.hi = bf16(hi).
__device__ __forceinline__ u32 cvtpk_bf16(float lo, float hi) {
    u32 r;
    asm("v_cvt_pk_bf16_f32 %0, %1, %2" : "=v"(r) : "v"(lo), "v"(hi));
    return r;
}
__device__ __forceinline__ f32x4 mfma16x16x32(short8 a, short8 b, f32x4 c) {
    return __builtin_amdgcn_mfma_f32_16x16x32_bf16(a, b, c, 0, 0, 0);
}
// Async global->LDS, 16B per lane. LDS dest = (wave-uniform base) + lane*16.
typedef const __attribute__((address_space(1))) u32 gu32;
typedef __attribute__((address_space(3))) u32 lu32;
__device__ __forceinline__ void async16(const ushort_t* g, ushort_t* l) {
    __builtin_amdgcn_global_load_lds((gu32*)g, (lu32*)l, 16, 0, 0);
}

// ---------------------------------------------------------------------------
// cast3: f32 -> bf16, 8 elements/thread, 3 tensors via blockIdx.z
// ---------------------------------------------------------------------------
__global__ __launch_bounds__(256)
void cast3(const float* __restrict__ A0, const float* __restrict__ A1,
           const float* __restrict__ A2, ushort_t* __restrict__ O0,
           ushort_t* __restrict__ O1, ushort_t* __restrict__ O2) {
    const float* A; ushort_t* O;
    switch (blockIdx.z) {
        case 0: A = A0; O = O0; break;
        case 1: A = A1; O = O1; break;
        default: A = A2; O = O2; break;
    }
    size_t idx = ((size_t)blockIdx.x * 256 + threadIdx.x) * 8;
    f32x4 v0 = *(const f32x4_ma*)(A + idx);
    f32x4 v1 = *(const f32x4_ma*)(A + idx + 4);
    u32x4 pk;
    pk[0] = pack2bf(v0[0], v0[1]);
    pk[1] = pack2bf(v0[2], v0[3]);
    pk[2] = pack2bf(v1[0], v1[1]);
    pk[3] = pack2bf(v1[2], v1[3]);
    *(u32x4_ma*)(O + idx) = pk;
}

// ---------------------------------------------------------------------------
// Weight transpose + f32->bf16: Wt[n][k] = bf16(W[k][n]), 1024x1024, 4 matrices
// ---------------------------------------------------------------------------
__global__ __launch_bounds__(256)
void transpose4(const float* __restrict__ W0, const float* __restrict__ W1,
                const float* __restrict__ W2, const float* __restrict__ W3,
                ushort_t* __restrict__ T0, ushort_t* __restrict__ T1,
                ushort_t* __restrict__ T2, ushort_t* __restrict__ T3) {
    __shared__ ushort_t tile[64][65];
    const float* W; ushort_t* T;
    switch (blockIdx.z) {
        case 0: W = W0; T = T0; break;
        case 1: W = W1; T = T1; break;
        case 2: W = W2; T = T2; break;
        default: W = W3; T = T3; break;
    }
    int bx = blockIdx.x * 64, by = blockIdx.y * 64;
    int tx = threadIdx.x & 63, ty = threadIdx.x >> 6;
    #pragma unroll
    for (int i = 0; i < 64; i += 4)
        tile[ty + i][tx] = f2bf(W[(size_t)(by + ty + i) * 1024 + bx + tx]);
    __syncthreads();
    #pragma unroll
    for (int i = 0; i < 64; i += 4)
        T[(size_t)(bx + ty + i) * 1024 + by + tx] = tile[tx][ty + i];
}

// ---------------------------------------------------------------------------
// vtrans: per (b,h) transpose V head-slice [2048 kr][64 d] -> VtG [64 d][2048 kr]
// ---------------------------------------------------------------------------
__global__ __launch_bounds__(256)
void vtrans(const ushort_t* __restrict__ V, ushort_t* __restrict__ VtG) {
    __shared__ ushort_t tile[64][65];
    int kt = blockIdx.x;          // 0..31
    int bh = blockIdx.y;          // 0..63
    int b = bh >> 4, h = bh & 15;
    int tx = threadIdx.x & 63, ty = threadIdx.x >> 6;
    #pragma unroll
    for (int i = 0; i < 64; i += 4)
        tile[ty + i][tx] = V[(size_t)(b * 2048 + kt * 64 + ty + i) * 1024 + h * 64 + tx];
    __syncthreads();
    #pragma unroll
    for (int i = 0; i < 64; i += 4)
        VtG[((size_t)bh * 64 + ty + i) * 2048 + kt * 64 + tx] = tile[tx][ty + i];
}

// ---------------------------------------------------------------------------
// GEMM (all-bf16 inputs): C[M,N] = A[M,K] @ Bt[N,K]^T + bias[N]
// T3 minimum 2-phase: double-buffered LDS, prefetch k0+64 issued right after
// the single per-K-step barrier, compute runs under the in-flight loads.
// Chunk c of row r lives at slot c ^ (r&7) (gptr-side swizzle): b128 fragment
// reads hit exactly 8 accesses/bank (minimum) -> conflict-free.
// ---------------------------------------------------------------------------
template<bool C_F32>
__global__ __launch_bounds__(256)
void gemm_async(const ushort_t* __restrict__ A, const ushort_t* __restrict__ Bt,
                const float* __restrict__ bias, void* __restrict__ Cab,
                int M, int N, int K, float outscale) {
    __shared__ __align__(16) ushort_t As[2][128 * 64];
    __shared__ __align__(16) ushort_t Bs[2][128 * 64];
    const int t = threadIdx.x;
    const int m0 = blockIdx.y * 128, n0 = blockIdx.x * 128;
    const int w = t >> 6, lane = t & 63, quad = lane >> 4, lr = lane & 15;
    const int wm = (w >> 1) * 64, wn = (w & 1) * 64;
    const int lrow8 = lane >> 3, lchunk = lane & 7;
    const int sw = (lchunk ^ lrow8) * 8;

    f32x4 acc[4][4] = {};

    // prologue: stage k0 = 0 into buffer 0
    #pragma unroll
    for (int i = 0; i < 4; i++) {
        int ra = 32 * w + 8 * i + lrow8;           // ra&7 == lrow8
        async16(A  + (size_t)(m0 + ra) * K + sw, &As[0][(32 * w + 8 * i) * 64]);
        async16(Bt + (size_t)(n0 + ra) * K + sw, &Bs[0][(32 * w + 8 * i) * 64]);
    }

    int cur = 0;
    for (int k0 = 0; k0 < K; k0 += 64) {
        __syncthreads();   // compiler drains vmcnt here: buf[cur] is ready
        if (k0 + 64 < K) {
            int nxt = cur ^ 1;
            #pragma unroll
            for (int i = 0; i < 4; i++) {
                int ra = 32 * w + 8 * i + lrow8;
                async16(A  + (size_t)(m0 + ra) * K + k0 + 64 + sw, &As[nxt][(32 * w + 8 * i) * 64]);
                async16(Bt + (size_t)(n0 + ra) * K + k0 + 64 + sw, &Bs[nxt][(32 * w + 8 * i) * 64]);
            }
        }
        #pragma unroll
        for (int kc = 0; kc < 2; kc++) {
            short8 af[4], bf[4];
            int pa = ((4 * kc + quad) ^ (lr & 7)) * 8;
            #pragma unroll
            for (int i = 0; i < 4; i++) {
                af[i] = *(const short8_ma*)(As[cur] + (wm + i * 16 + lr) * 64 + pa);
                bf[i] = *(const short8_ma*)(Bs[cur] + (wn + i * 16 + lr) * 64 + pa);
            }
            #pragma unroll
            for (int i = 0; i < 4; i++)
                #pragma unroll
                for (int j = 0; j < 4; j++)
                    acc[i][j] = mfma16x16x32(af[i], bf[j], acc[i][j]);
        }
        cur ^= 1;
    }

    // Epilogue: C/D layout row = quad*4 + reg, col = lane&15
    #pragma unroll
    for (int i = 0; i < 4; i++) {
        int row = m0 + wm + i * 16 + quad * 4;
        #pragma unroll
        for (int j = 0; j < 4; j++) {
            int col = n0 + wn + j * 16 + lr;
            float bv = bias[col];
            #pragma unroll
            for (int r = 0; r < 4; r++) {
                size_t idx = (size_t)(row + r) * N + col;
                if (C_F32) ((float*)Cab)[idx] = acc[i][j][r] + bv;
                else ((ushort_t*)Cab)[idx] = f2bf((acc[i][j][r] + bv) * outscale);
            }
        }
    }
}

// ---------------------------------------------------------------------------
// Flash attention v3: S^T = K.Q^T, O^T = V^T.P^T (alpha/l per-lane).
// Changes this round (VALU-bound per rocprof: VALUBusy 56%, MfmaUtil 17%):
//  - K/V double-buffered, single barrier per kt, prefetch kt+1 under compute.
//  - P packing via v_cvt_pk_bf16_f32 (1 op/pair vs 5 for manual RNE).
//  - defer-max (THR=8 in log2 domain): skip alpha rescale of oacc/lrow when
//    the running max doesn't grow past THR (wave-uniform __all).
//  - max reduction as nested fmax triples -> v_max3_f32.
// ---------------------------------------------------------------------------
__global__ __launch_bounds__(256)
void attn_fwd(const ushort_t* __restrict__ Q, const ushort_t* __restrict__ Kg,
              const ushort_t* __restrict__ VtG, ushort_t* __restrict__ Z) {
    __shared__ __align__(16) ushort_t Ks[2][64 * 64];   // [buf][krow][d]
    __shared__ __align__(16) ushort_t Vt[2][64 * 64];   // [buf][d][krow]
    __shared__ __align__(16) ushort_t Pt[128 * 64];     // [qrow][krow] (wave-private rows)

    const int t = threadIdx.x;
    const int qt = blockIdx.x;        // 0..15
    const int bh = blockIdx.y;        // 0..63
    const int b = bh >> 4, h = bh & 15;
    const int w = t >> 6, lane = t & 63, quad = lane >> 4, lr = lane & 15;
    const int lrow8 = lane >> 3, lchunk = lane & 7;

    const size_t rs = 1024;
    const size_t qbase = ((size_t)b * 2048 + qt * 128) * rs + h * 64;
    const size_t kvbase = ((size_t)b * 2048) * rs + h * 64;
    const size_t vbase = (size_t)bh * 64 * 2048;

    // Q fragments (B-operand of S^T: n = lr = qrow, k = quad*8+j = d)
    short8 qf[2][2];
    #pragma unroll
    for (int mt = 0; mt < 2; mt++)
        #pragma unroll
        for (int kc = 0; kc < 2; kc++)
            qf[mt][kc] = *(const short8_ma*)(Q + qbase + (size_t)(w * 32 + mt * 16 + lr) * rs + kc * 32 + quad * 8);

    f32x4 oacc[2][4] = {};   // oacc[mt][dn] = O^T[d = dn*16+quad*4+r][qrow = w*32+mt*16+lr]
    float mrow[2] = { -INFINITY, -INFINITY };
    float lrow[2] = { 0.f, 0.f };

    const int rloc0 = 16 * w + lrow8;          // rloc&7 == lrow8
    const int sw = (lchunk ^ lrow8) * 8;

    // prologue: stage kt=0 into buffer 0
    #pragma unroll
    for (int i = 0; i < 2; i++) {
        int rloc = rloc0 + 8 * i;
        async16(Kg + kvbase + (size_t)rloc * rs + sw, &Ks[0][(16 * w + 8 * i) * 64]);
        async16(VtG + vbase + (size_t)rloc * 2048 + sw, &Vt[0][(16 * w + 8 * i) * 64]);
    }

    int cur = 0;
    for (int kt = 0; kt < 32; kt++) {
        __syncthreads();   // compiler drains vmcnt+lgkm: buf[cur] ready
        if (kt < 31) {
            int nxt = cur ^ 1;
            #pragma unroll
            for (int i = 0; i < 2; i++) {
                int rloc = rloc0 + 8 * i;
                async16(Kg + kvbase + (size_t)((kt + 1) * 64 + rloc) * rs + sw, &Ks[nxt][(16 * w + 8 * i) * 64]);
                async16(VtG + vbase + (size_t)rloc * 2048 + (kt + 1) * 64 + sw, &Vt[nxt][(16 * w + 8 * i) * 64]);
            }
        }
        const ushort_t* Kc = Ks[cur];
        const ushort_t* Vc = Vt[cur];

        // S^T = K.Q^T : sacc[nt][mt] rows = krow (nt*16+quad*4+r), cols = qrow (mt*16+lr)
        f32x4 sacc[4][2] = {};
        #pragma unroll
        for (int kc = 0; kc < 2; kc++) {
            short8 kf[4];
            int pa = ((4 * kc + quad) ^ (lr & 7)) * 8;
            #pragma unroll
            for (int nt = 0; nt < 4; nt++)
                kf[nt] = *(const short8_ma*)(Kc + (nt * 16 + lr) * 64 + pa);
            #pragma unroll
            for (int nt = 0; nt < 4; nt++)
                #pragma unroll
                for (int mt = 0; mt < 2; mt++)
                    sacc[nt][mt] = mfma16x16x32(kf[nt], qf[mt][kc], sacc[nt][mt]);
        }

        // online softmax per qrow (per-lane: qrow = w*32+mt*16+lr)
        #pragma unroll
        for (int mt = 0; mt < 2; mt++) {
            // v_max3-friendly reduction tree over the 16 regs
            float a0 = fmaxf(fmaxf(sacc[0][mt][0], sacc[0][mt][1]), sacc[0][mt][2]);
            float a1 = fmaxf(fmaxf(sacc[0][mt][3], sacc[1][mt][0]), sacc[1][mt][1]);
            float a2 = fmaxf(fmaxf(sacc[1][mt][2], sacc[1][mt][3]), sacc[2][mt][0]);
            float a3 = fmaxf(fmaxf(sacc[2][mt][1], sacc[2][mt][2]), sacc[2][mt][3]);
            float a4 = fmaxf(fmaxf(sacc[3][mt][0], sacc[3][mt][1]), sacc[3][mt][2]);
            float b0 = fmaxf(fmaxf(a0, a1), a2);
            float b1 = fmaxf(fmaxf(a3, a4), sacc[3][mt][3]);
            float mx = fmaxf(b0, b1);
            mx = fmaxf(mx, __shfl_xor(mx, 16, 64));
            mx = fmaxf(mx, __shfl_xor(mx, 32, 64));

            // defer-max: skip the O/l rescale while max growth <= 8 (log2 domain,
            // P then bounded by 2^8 -- fine in bf16/f32). Wave-uniform branch.
            if (!__all(mx <= mrow[mt] + 8.0f)) {
                float mnew = fmaxf(mrow[mt], mx);
                float alpha = EXP2(mrow[mt] - mnew);
                mrow[mt] = mnew;
                lrow[mt] *= alpha;
                oacc[mt][0] *= alpha;
                oacc[mt][1] *= alpha;
                oacc[mt][2] *= alpha;
                oacc[mt][3] *= alpha;
            }
            const float mcur = mrow[mt];

            float rsum = 0.f;
            const int prow = w * 32 + mt * 16 + lr;
            #pragma unroll
            for (int nt = 0; nt < 4; nt++) {
                float p0 = EXP2(sacc[nt][mt][0] - mcur);
                float p1 = EXP2(sacc[nt][mt][1] - mcur);
                float p2 = EXP2(sacc[nt][mt][2] - mcur);
                float p3 = EXP2(sacc[nt][mt][3] - mcur);
                rsum += (p0 + p1) + (p2 + p3);
                u32x2 pw;
                pw[0] = cvtpk_bf16(p0, p1);
                pw[1] = cvtpk_bf16(p2, p3);
                int phys = (2 * nt + (quad >> 1)) ^ (lr & 7);
                *(u32x2_ma*)(Pt + prow * 64 + phys * 8 + (quad & 1) * 4) = pw;
            }
            rsum += __shfl_xor(rsum, 16, 64);
            rsum += __shfl_xor(rsum, 32, 64);
            lrow[mt] += rsum;
        }

        // order P writes before P reads (same-wave DS pipe is in-order)
        asm volatile("" ::: "memory");

        // O^T += V^T.P^T  (A = V^T frag, B = P^T frag)
        #pragma unroll
        for (int kc2 = 0; kc2 < 2; kc2++) {
            short8 pf[2], vf[4];
            int pp = ((4 * kc2 + quad) ^ (lr & 7)) * 8;
            #pragma unroll
            for (int mt = 0; mt < 2; mt++)
                pf[mt] = *(const short8_ma*)(Pt + (w * 32 + mt * 16 + lr) * 64 + pp);
            #pragma unroll
            for (int dn = 0; dn < 4; dn++)
                vf[dn] = *(const short8_ma*)(Vc + (dn * 16 + lr) * 64 + pp);
            #pragma unroll
            for (int mt = 0; mt < 2; mt++)
                #pragma unroll
                for (int dn = 0; dn < 4; dn++)
                    oacc[mt][dn] = mfma16x16x32(vf[dn], pf[mt], oacc[mt][dn]);
        }
        cur ^= 1;
    }

    // Epilogue: normalize (per-lane l), transpose O^T through LDS, store coalesced.
    ushort_t* Ot = Pt;  // reuse; rows are wave-private (qrows w*32..w*32+31)
    float inv[2] = { 1.f / lrow[0], 1.f / lrow[1] };
    asm volatile("" ::: "memory");
    #pragma unroll
    for (int mt = 0; mt < 2; mt++)
        #pragma unroll
        for (int dn = 0; dn < 4; dn++) {
            u32x2 pw;
            pw[0] = cvtpk_bf16(oacc[mt][dn][0] * inv[mt], oacc[mt][dn][1] * inv[mt]);
            pw[1] = cvtpk_bf16(oacc[mt][dn][2] * inv[mt], oacc[mt][dn][3] * inv[mt]);
            int phys = (2 * dn + (quad >> 1)) ^ (lr & 7);
            *(u32x2_ma*)(Ot + (w * 32 + mt * 16 + lr) * 64 + phys * 8 + (quad & 1) * 4) = pw;
        }
    asm volatile("" ::: "memory");
    {
        int qrow = t >> 1;            // wave w reads back its own rows 32w..32w+31
        int dhalf = (t & 1) * 32;
        #pragma unroll
        for (int cc = 0; cc < 4; cc++) {
            int phys = ((4 * (t & 1) + cc) ^ (qrow & 7)) * 8;
            short8 v = *(const short8_ma*)(Ot + qrow * 64 + phys);
            *(short8_ma*)(Z + qbase + (size_t)qrow * rs + dhalf + cc * 8) = v;
        }
    }
}

// ---------------------------------------------------------------------------
extern "C" void kernel_launch(void* const* d_in, const int* in_sizes, int n_in,
                              void* d_out, int out_size, void* d_ws, size_t ws_size,
                              hipStream_t stream) {
    const float* query = (const float*)d_in[0];
    const float* key   = (const float*)d_in[1];
    const float* value = (const float*)d_in[2];
    const float* Wq = (const float*)d_in[3];
    const float* bq = (const float*)d_in[4];
    const float* Wk = (const float*)d_in[5];
    const float* bk = (const float*)d_in[6];
    const float* Wv = (const float*)d_in[7];
    const float* bv = (const float*)d_in[8];
    const float* Wo = (const float*)d_in[9];
    const float* bo = (const float*)d_in[10];
    float* out = (float*)d_out;

    char* ws = (char*)d_ws;
    const size_t WSZ = 1024ull * 1024 * 2;
    const size_t QSZ = 8192ull * 1024 * 2;
    const size_t BW = 4 * WSZ;
    ushort_t* WqT = (ushort_t*)(ws + 0 * WSZ);
    ushort_t* WkT = (ushort_t*)(ws + 1 * WSZ);
    ushort_t* WvT = (ushort_t*)(ws + 2 * WSZ);
    ushort_t* WoT = (ushort_t*)(ws + 3 * WSZ);
    // Buffer lifetime aliasing (max live = 4 activations = 75.5 MB total ws):
    ushort_t* S1 = (ushort_t*)(ws + BW + 0 * QSZ);  // Qbf  -> Kws
    ushort_t* S2 = (ushort_t*)(ws + BW + 1 * QSZ);  // Kbf  -> Vws
    ushort_t* S3 = (ushort_t*)(ws + BW + 2 * QSZ);  // Vbf  -> VtG
    ushort_t* S4 = (ushort_t*)(ws + BW + 3 * QSZ);  // Qws  (= Z)

    cast3<<<dim3(4096, 1, 3), 256, 0, stream>>>(query, key, value, S1, S2, S3);
    transpose4<<<dim3(16, 16, 4), 256, 0, stream>>>(Wq, Wk, Wv, Wo, WqT, WkT, WvT, WoT);

    dim3 gg(8, 64);
    // Q projection carries 1/sqrt(64) * log2(e): softmax runs in exp2 domain
    gemm_async<false><<<gg, 256, 0, stream>>>(S1, WqT, bq, S4, 8192, 1024, 1024, 0.125f * 1.4426950408889634f);
    gemm_async<false><<<gg, 256, 0, stream>>>(S2, WkT, bk, S1, 8192, 1024, 1024, 1.0f);
    gemm_async<false><<<gg, 256, 0, stream>>>(S3, WvT, bv, S2, 8192, 1024, 1024, 1.0f);

    vtrans<<<dim3(32, 64), 256, 0, stream>>>(S2, S3);

    attn_fwd<<<dim3(16, 64), 256, 0, stream>>>(S4, S1, S3, S4);

    gemm_async<true><<<gg, 256, 0, stream>>>(S4, WoT, bo, out, 8192, 1024, 1024, 1.0f);
}